// Round 13
// baseline (1135.646 us; speedup 1.0000x reference)
//
#include <hip/hip_runtime.h>
#include <hip/hip_bf16.h>
#include <cmath>

// ---------------------------------------------------------------------------
// Sizes
// ---------------------------------------------------------------------------
#define DS 1200     // signal dim
#define DD 2400     // dict dim
#define MR 2048     // rows (B*N)
#define KP 1216     // padded signal dim (38*32)
#define NP1 1280    // padded signal dim for recon B panel (10*128)
#define NG 2432     // padded dict dim (19*128 = 38*64)
#define PPI 150     // norm partials per power iteration

typedef __attribute__((ext_vector_type(8))) short s16x8;
typedef __attribute__((ext_vector_type(4))) float f32x4;

__device__ __forceinline__ float s2f(short s) {
    union { unsigned u; float f; } c;
    c.u = ((unsigned)(unsigned short)s) << 16;
    return c.f;
}
__device__ __forceinline__ short f2s(float f) {
    __hip_bfloat16 h = __float2bfloat16(f);
    return *reinterpret_cast<short*>(&h);
}

// Packed layout: 128-row bands; within a band, 8-col k-subtiles of 1024 elems:
//   poff(m,k,C) = (m&~127)*C + (k>>3)*1024 + (m&127)*8 + (k&7)

// ---------------------------------------------------------------------------
// JAX threefry2x32 + XLA f32 erfinv (reproduce jax.random.normal(key(42)))
// ---------------------------------------------------------------------------
__device__ __forceinline__ unsigned rotl32(unsigned x, int d) {
    return (x << d) | (x >> (32 - d));
}

__device__ void threefry2x32(unsigned k0, unsigned k1, unsigned x0, unsigned x1,
                             unsigned* o0, unsigned* o1) {
    unsigned ks0 = k0, ks1 = k1, ks2 = k0 ^ k1 ^ 0x1BD11BDAu;
    const int rotA[4] = {13, 15, 26, 6};
    const int rotB[4] = {17, 29, 16, 24};
    x0 += ks0; x1 += ks1;
    #pragma unroll
    for (int r = 0; r < 4; r++) { x0 += x1; x1 = rotl32(x1, rotA[r]); x1 ^= x0; }
    x0 += ks1; x1 += ks2 + 1u;
    #pragma unroll
    for (int r = 0; r < 4; r++) { x0 += x1; x1 = rotl32(x1, rotB[r]); x1 ^= x0; }
    x0 += ks2; x1 += ks0 + 2u;
    #pragma unroll
    for (int r = 0; r < 4; r++) { x0 += x1; x1 = rotl32(x1, rotA[r]); x1 ^= x0; }
    x0 += ks0; x1 += ks1 + 3u;
    #pragma unroll
    for (int r = 0; r < 4; r++) { x0 += x1; x1 = rotl32(x1, rotB[r]); x1 ^= x0; }
    x0 += ks1; x1 += ks2 + 4u;
    #pragma unroll
    for (int r = 0; r < 4; r++) { x0 += x1; x1 = rotl32(x1, rotA[r]); x1 ^= x0; }
    x0 += ks2; x1 += ks0 + 5u;
    *o0 = x0; *o1 = x1;
}

__device__ float erfinv_f32(float x) {
    float w = -logf((1.0f - x) * (1.0f + x));
    float p;
    if (w < 5.0f) {
        w -= 2.5f;
        p = 2.81022636e-08f;
        p = fmaf(p, w, 3.43273939e-07f);
        p = fmaf(p, w, -3.5233877e-06f);
        p = fmaf(p, w, -4.39150654e-06f);
        p = fmaf(p, w, 0.00021858087f);
        p = fmaf(p, w, -0.00125372503f);
        p = fmaf(p, w, -0.00417768164f);
        p = fmaf(p, w, 0.246640727f);
        p = fmaf(p, w, 1.50140941f);
    } else {
        w = sqrtf(w) - 3.0f;
        p = -0.000200214257f;
        p = fmaf(p, w, 0.000100950558f);
        p = fmaf(p, w, 0.00134934322f);
        p = fmaf(p, w, -0.00367342844f);
        p = fmaf(p, w, 0.00573950773f);
        p = fmaf(p, w, -0.0076224613f);
        p = fmaf(p, w, 0.00943887047f);
        p = fmaf(p, w, 1.00167406f);
        p = fmaf(p, w, 2.83297682f);
    }
    return p * x;
}

__device__ float bits_to_normal(unsigned bits) {
    unsigned fb = (bits >> 9) | 0x3F800000u;
    float u01 = __uint_as_float(fb) - 1.0f;
    const float lo = -0.99999994f;
    float u = u01 * 2.0f + lo;
    u = fmaxf(lo, u);
    return 1.41421356237f * erfinv_f32(u);
}

// ---------------------------------------------------------------------------
// Power iteration (20-launch chain, deterministic fixed-slot partials)
// ---------------------------------------------------------------------------
__global__ void k_init(float* __restrict__ w0, float* __restrict__ w1,
                       float* __restrict__ part) {
    int tid = threadIdx.x;
    for (int i = tid; i < 21 * PPI; i += 256) part[i] = 0.0f;
    if (tid < 32) {
        w0[2400 + tid] = 0.0f;
        w1[2400 + tid] = 0.0f;
    }
    __shared__ float red[256];
    float local2 = 0.0f;
    for (int p = tid; p < DS; p += 256) {
        unsigned r0, r1;
        threefry2x32(0u, 42u, (unsigned)p, (unsigned)(DS + p), &r0, &r1);
        float n0 = bits_to_normal(r0);
        float n1 = bits_to_normal(r1);
        w0[p] = n0;
        w0[DS + p] = n1;
        local2 += n0 * n0 + n1 * n1;
    }
    red[tid] = local2;
    __syncthreads();
    for (int s = 128; s > 0; s >>= 1) {
        if (tid < s) red[tid] += red[tid + s];
        __syncthreads();
    }
    if (tid == 0) part[0] = red[0];
}

__global__ __launch_bounds__(1024) void k_gmv(const short* __restrict__ Grm,
                                              const float* __restrict__ win,
                                              const float* __restrict__ partin,
                                              float* __restrict__ wout,
                                              float* __restrict__ partout) {
    float s2 = 0.0f;
    for (int i = 0; i < PPI; i++) s2 += partin[i];
    float rn = 1.0f / sqrtf(s2);
    int wave = threadIdx.x >> 6, lane = threadIdx.x & 63;
    int row = blockIdx.x * 16 + wave;       // 150 * 16 = 2400 rows
    const s16x8* gh = (const s16x8*)(Grm + (size_t)row * NG);
    const float4* w4 = (const float4*)win;
    float acc = 0.0f;
    #pragma unroll
    for (int i = 0; i < 5; i++) {
        int c = lane + i * 64;              // 304 chunks
        if (c < 304) {
            s16x8 h = gh[c];
            float4 wa = w4[c * 2], wb = w4[c * 2 + 1];
            acc += s2f(h[0]) * wa.x + s2f(h[1]) * wa.y;
            acc += s2f(h[2]) * wa.z + s2f(h[3]) * wa.w;
            acc += s2f(h[4]) * wb.x + s2f(h[5]) * wb.y;
            acc += s2f(h[6]) * wb.z + s2f(h[7]) * wb.w;
        }
    }
    #pragma unroll
    for (int off = 32; off > 0; off >>= 1) acc += __shfl_xor(acc, off, 64);
    __shared__ float red[16];
    if (lane == 0) {
        float val = acc * rn;
        wout[row] = val;
        red[wave] = val * val;
    }
    __syncthreads();
    if (threadIdx.x == 0) {
        float s = 0.0f;
        #pragma unroll
        for (int i = 0; i < 16; i++) s += red[i];
        partout[blockIdx.x] = s;
    }
}

__global__ void k_fin(const float* __restrict__ part20, float* __restrict__ scal) {
    if (threadIdx.x == 0) {
        float s = 0.0f;
        for (int i = 0; i < PPI; i++) s += part20[i];
        float L = sqrtf(s);
        scal[0] = L;
        scal[1] = 1.0f / L;
        scal[2] = 0.1f / L;
    }
}

// ---------------------------------------------------------------------------
// Prep kernels (write packed layouts)
// ---------------------------------------------------------------------------
__global__ void k_makeD(const float* __restrict__ D, short* __restrict__ Dp) {
    int p = blockIdx.x * 256 + threadIdx.x;     // NP1*NG
    if (p >= NP1 * NG) return;
    int tile = p >> 10, win = p & 1023;
    int row = win >> 3, e = win & 7;
    int mt = tile / (NG >> 3), ct = tile % (NG >> 3);
    int d = mt * 128 + row, n = ct * 8 + e;
    float v = (d < DS && n < DD) ? D[(size_t)d * DD + n] : 0.0f;
    Dp[p] = f2s(v);
}

// X packed single-bf16 (A operand of XDL GEMM)
__global__ void k_makeX(const float* __restrict__ x, short* __restrict__ Xp) {
    int p = blockIdx.x * 256 + threadIdx.x;     // MR*KP
    if (p >= MR * KP) return;
    int tile = p >> 10, win = p & 1023;
    int row = win >> 3, e = win & 7;
    int mt = tile / (KP >> 3), ct = tile % (KP >> 3);
    int m = mt * 128 + row, k = ct * 8 + e;
    float v = (k < DS) ? x[(size_t)m * DS + k] : 0.0f;
    Xp[p] = f2s(v);
}

__global__ void k_makeDt(const float* __restrict__ D,
                         short* __restrict__ Dthi, short* __restrict__ Dtlo) {
    __shared__ float t[32][33];
    int bc = blockIdx.x * 32;   // dict base
    int bk = blockIdx.y * 32;   // signal base
    int tx = threadIdx.x & 31, ty = threadIdx.x >> 5;
    for (int i = ty; i < 32; i += 8) {
        int k = bk + i, c = bc + tx;
        t[i][tx] = (k < DS && c < DD) ? D[(size_t)k * DD + c] : 0.0f;
    }
    __syncthreads();
    for (int i = ty; i < 32; i += 8) {
        int c = bc + i, k = bk + tx;
        float v = t[tx][i];
        short h = f2s(v);
        size_t po = ((size_t)(c >> 7) * (KP >> 3) + (k >> 3)) * 1024 +
                    ((c & 127) << 3) + (k & 7);
        Dthi[po] = h;
        Dtlo[po] = f2s(v - s2f(h));
    }
}

// W = I - G/L, bf16 packed layout, from bf16 row-major Grm.
__global__ void k_makeW(const short* __restrict__ Grm, const float* __restrict__ scal,
                        short* __restrict__ Wp) {
    int i = blockIdx.x * 256 + threadIdx.x;      // over NG*NG/8
    if (i >= NG * NG / 8) return;
    float invL = scal[1];
    int e0 = i * 8;
    int band = e0 / (128 * NG);
    int rem = e0 - band * (128 * NG);
    int tile = rem >> 10;
    int row = (rem & 1023) >> 3;
    int m = band * 128 + row;       // W row (output index n)
    int k0 = tile * 8;              // W col (contraction index k)
    s16x8 g = *(const s16x8*)(Grm + (size_t)m * NG + k0);
    s16x8 wv;
    #pragma unroll
    for (int e = 0; e < 8; e++) {
        float wf = ((k0 + e == m) ? 1.0f : 0.0f) - s2f(g[e]) * invL;
        wv[e] = f2s(wf);
    }
    ((s16x8*)Wp)[i] = wv;
}

// FISTA iteration 0 (y0=0): z1 = soft(XDL, thr); y1 = z1.
__global__ void k_fista0(const short* __restrict__ XDL, const float* __restrict__ scal,
                         short* __restrict__ Z, short* __restrict__ Y) {
    int i = blockIdx.x * 256 + threadIdx.x;      // over MR*NG/8
    if (i >= MR * NG / 8) return;
    float thr = scal[2];
    s16x8 xv = ((const s16x8*)XDL)[i];
    s16x8 zs;
    #pragma unroll
    for (int k = 0; k < 8; k++) {
        float gs = s2f(xv[k]);
        float az = fabsf(gs) - thr;
        float zn = (az > 0.0f) ? copysignf(az, gs) : 0.0f;
        zs[k] = f2s(zn);
    }
    ((s16x8*)Z)[i] = zs;
    ((s16x8*)Y)[i] = zs;
}

// ---------------------------------------------------------------------------
__device__ __forceinline__ void gload16(const void* g, void* l) {
    __builtin_amdgcn_global_load_lds(
        (const __attribute__((address_space(1))) unsigned int*)g,
        (__attribute__((address_space(3))) unsigned int*)l, 16, 0, 0);
}

// ---------------------------------------------------------------------------
// FISTA GEMM (A-in-registers variant of the R12 structure; single delta).
// Tile 64(M)x128(N), BK=64, 4 waves (32x64). A (y) via global->register with
// one-tile ping-pong prefetch; B (W) via 2 x 16 KB LDS double buffer.
// Swizzle, launch bounds, barriers, epilogue identical to R12's EPI2/EPI5.
// ---------------------------------------------------------------------------
__global__ __launch_bounds__(256, 4) void fista_gemm(
    const short* __restrict__ Yp, const short* __restrict__ Wq,
    const short* __restrict__ XDLp, const float* __restrict__ scal, float mom,
    short* __restrict__ Ynew, short* __restrict__ Zst, int lastIter) {
    __shared__ __align__(16) short ldsB[2][8192];   // 2 x 16 KB (B tile 128x64)

    const int tid = threadIdx.x;
    const int w = tid >> 6, lane = tid & 63;
    const int fm = lane & 15, kg = lane >> 4;
    const int wr = w >> 1, wc = w & 1;

    // R12/R7 swizzle: grid 608 divisible by 8
    const int q = 76;
    const int s = (blockIdx.x & 7) * q + (blockIdx.x >> 3);
    const int by = s & 31, bx = s >> 5;
    const int m0 = by * 64, n0 = bx * 128;

    f32x4 acc[2][4];
    #pragma unroll
    for (int g = 0; g < 2; ++g)
        #pragma unroll
        for (int h = 0; h < 4; ++h) acc[g][h] = f32x4{0.f, 0.f, 0.f, 0.f};

    const float thr = scal[2];

    const int band = m0 & ~127, half = (m0 >> 6) & 1;
    const int mloc = half * 64 + wr * 32 + fm;
    // A frag (tile t, ks, g) at: Ab + (t*8 + ks*4 + kg)*1024 + g*128
    const short* Ab = Yp + (size_t)band * NG + mloc * 8 + kg * 1024;
    const short* Bb = Wq + (size_t)n0 * NG + tid * 8;   // staging source

    s16x8 A0_0, A0_1, A0_2, A0_3;   // even-tile regs: [ks*2+g]
    s16x8 A1_0, A1_1, A1_2, A1_3;   // odd-tile regs

#define LOADA(st, r0, r1, r2, r3)                           \
    {                                                       \
        const short* p_ = Ab + (size_t)(st) * 8192;         \
        r0 = *(const s16x8*)(p_);                           \
        r1 = *(const s16x8*)(p_ + 128);                     \
        r2 = *(const s16x8*)(p_ + 4096);                    \
        r3 = *(const s16x8*)(p_ + 4224);                    \
    }
#define STAGEB(st, buf)                                     \
    {                                                       \
        const short* q_ = Bb + (size_t)(st) * 8192;         \
        short* bp_ = &ldsB[buf][0];                         \
        gload16(q_,        bp_ + w * 512);                  \
        gload16(q_ + 2048, bp_ + 2048 + w * 512);           \
        gload16(q_ + 4096, bp_ + 4096 + w * 512);           \
        gload16(q_ + 6144, bp_ + 6144 + w * 512);           \
    }
#define COMP(buf, r0, r1, r2, r3)                                              \
    {                                                                          \
        const short* bs_ = &ldsB[buf][0];                                      \
        {                                                                      \
            const int c_ = kg;                                                 \
            s16x8 b0 = *(const s16x8*)&bs_[c_ * 1024 + (wc * 64 + 0 * 16 + fm) * 8];  \
            s16x8 b1 = *(const s16x8*)&bs_[c_ * 1024 + (wc * 64 + 1 * 16 + fm) * 8];  \
            s16x8 b2 = *(const s16x8*)&bs_[c_ * 1024 + (wc * 64 + 2 * 16 + fm) * 8];  \
            s16x8 b3 = *(const s16x8*)&bs_[c_ * 1024 + (wc * 64 + 3 * 16 + fm) * 8];  \
            acc[0][0] = __builtin_amdgcn_mfma_f32_16x16x32_bf16(r0, b0, acc[0][0], 0, 0, 0); \
            acc[0][1] = __builtin_amdgcn_mfma_f32_16x16x32_bf16(r0, b1, acc[0][1], 0, 0, 0); \
            acc[0][2] = __builtin_amdgcn_mfma_f32_16x16x32_bf16(r0, b2, acc[0][2], 0, 0, 0); \
            acc[0][3] = __builtin_amdgcn_mfma_f32_16x16x32_bf16(r0, b3, acc[0][3], 0, 0, 0); \
            acc[1][0] = __builtin_amdgcn_mfma_f32_16x16x32_bf16(r1, b0, acc[1][0], 0, 0, 0); \
            acc[1][1] = __builtin_amdgcn_mfma_f32_16x16x32_bf16(r1, b1, acc[1][1], 0, 0, 0); \
            acc[1][2] = __builtin_amdgcn_mfma_f32_16x16x32_bf16(r1, b2, acc[1][2], 0, 0, 0); \
            acc[1][3] = __builtin_amdgcn_mfma_f32_16x16x32_bf16(r1, b3, acc[1][3], 0, 0, 0); \
        }                                                                      \
        {                                                                      \
            const int c_ = 4 + kg;                                             \
            s16x8 b0 = *(const s16x8*)&bs_[c_ * 1024 + (wc * 64 + 0 * 16 + fm) * 8];  \
            s16x8 b1 = *(const s16x8*)&bs_[c_ * 1024 + (wc * 64 + 1 * 16 + fm) * 8];  \
            s16x8 b2 = *(const s16x8*)&bs_[c_ * 1024 + (wc * 64 + 2 * 16 + fm) * 8];  \
            s16x8 b3 = *(const s16x8*)&bs_[c_ * 1024 + (wc * 64 + 3 * 16 + fm) * 8];  \
            acc[0][0] = __builtin_amdgcn_mfma_f32_16x16x32_bf16(r2, b0, acc[0][0], 0, 0, 0); \
            acc[0][1] = __builtin_amdgcn_mfma_f32_16x16x32_bf16(r2, b1, acc[0][1], 0, 0, 0); \
            acc[0][2] = __builtin_amdgcn_mfma_f32_16x16x32_bf16(r2, b2, acc[0][2], 0, 0, 0); \
            acc[0][3] = __builtin_amdgcn_mfma_f32_16x16x32_bf16(r2, b3, acc[0][3], 0, 0, 0); \
            acc[1][0] = __builtin_amdgcn_mfma_f32_16x16x32_bf16(r3, b0, acc[1][0], 0, 0, 0); \
            acc[1][1] = __builtin_amdgcn_mfma_f32_16x16x32_bf16(r3, b1, acc[1][1], 0, 0, 0); \
            acc[1][2] = __builtin_amdgcn_mfma_f32_16x16x32_bf16(r3, b2, acc[1][2], 0, 0, 0); \
            acc[1][3] = __builtin_amdgcn_mfma_f32_16x16x32_bf16(r3, b3, acc[1][3], 0, 0, 0); \
        }                                                                      \
    }

    LOADA(0, A0_0, A0_1, A0_2, A0_3);
    STAGEB(0, 0);

    for (int t = 0; t < 38; t += 2) {
        __syncthreads();                 // B(t) staged & visible
        STAGEB(t + 1, 1);                // prefetch B(t+1) under compute
        LOADA(t + 1, A1_0, A1_1, A1_2, A1_3);
        COMP(0, A0_0, A0_1, A0_2, A0_3);
        __syncthreads();                 // B(t+1) staged; buf0 free
        if (t + 2 < 38) {
            STAGEB(t + 2, 0);
            LOADA(t + 2, A0_0, A0_1, A0_2, A0_3);
        }
        COMP(1, A1_0, A1_1, A1_2, A1_3);
    }

#undef LOADA
#undef STAGEB
#undef COMP

    // epilogue: frag (row = kg*4+j, col = fm) -- identical to R12 EPI2/EPI5
    #pragma unroll
    for (int g = 0; g < 2; ++g) {
        #pragma unroll
        for (int h = 0; h < 4; ++h) {
            #pragma unroll
            for (int j = 0; j < 4; ++j) {
                int m = m0 + wr * 32 + g * 16 + kg * 4 + j;
                int n = n0 + wc * 64 + h * 16 + fm;
                float v = acc[g][h][j];
                size_t pz = (size_t)(m & ~127) * NG + ((n >> 3) << 10) +
                            ((m & 127) << 3) + (n & 7);
                float gs = v + s2f(XDLp[pz]);
                float az = fabsf(gs) - thr;
                float zn = (az > 0.0f) ? copysignf(az, gs) : 0.0f;
                if (!lastIter) {
                    float zold = s2f(Zst[pz]);
                    float yn = zn + mom * (zn - zold);
                    Zst[pz] = f2s(zn);
                    Ynew[pz] = f2s(yn);
                } else {
                    Zst[pz] = f2s(zn);
                }
            }
        }
    }
}

// ---------------------------------------------------------------------------
// MFMA GEMM on packed operands (R7-proven 2-buffer structure). Tile 64x128,
// 4 waves (32x64).
// SPLITM: 0 = single bf16 (BK=64), 1 = A&B hi/lo split (BK=32, 3 MFMA),
//         2 = B-only split (BK=32, 2 MFMA).
// EPI 0: Out[m*DS+n] = acc (n<DS)        (final recon)
// EPI 3: XDLout[pz] = bf16(acc*invL)     (XDL precompute; via Ynew)
// EPI 4: Grm[m*NG+n] = bf16(acc)         (G precompute)
// ---------------------------------------------------------------------------
template <int EPI, int SPLITM>
__global__ __launch_bounds__(256, 4) void mfma_gemm(
    const short* __restrict__ Ah, const short* __restrict__ Al, int CA,
    const short* __restrict__ Bh, const short* __restrict__ Bl, int CB,
    int K, int swz,
    const float* __restrict__ scal,
    short* __restrict__ Ynew,
    short* __restrict__ Grm,
    float* __restrict__ Out) {
    constexpr int ALO = 2048;
    constexpr int BHO = 4096;
    constexpr int BLO = 8192;
    constexpr int BUF = 12288;                // 24 KB per buffer
    __shared__ __align__(16) short lds[2 * BUF];

    const int tid = threadIdx.x;
    const int w = tid >> 6, lane = tid & 63;
    const int fm = lane & 15, kg = lane >> 4;
    const int wr = w >> 1, wc = w & 1;

    int bx, by;
    if (swz) {                                // grid divisible by 8
        int q = gridDim.x >> 3;
        int s = (blockIdx.x & 7) * q + (blockIdx.x >> 3);
        by = s & 31; bx = s >> 5;             // 32 M-blocks (M=2048)
    } else { bx = blockIdx.x; by = blockIdx.y; }
    const int m0 = by * 64, n0 = bx * 128;

    f32x4 acc[2][4];
    #pragma unroll
    for (int g = 0; g < 2; ++g)
        #pragma unroll
        for (int h = 0; h < 4; ++h) acc[g][h] = f32x4{0.f, 0.f, 0.f, 0.f};

    float invL = 0.0f;
    if (EPI == 3) invL = scal[1];

    const int half = (m0 >> 6) & 1;
    const int nk = K / (SPLITM ? 32 : 64);

    const size_t AbS = (size_t)(m0 & ~127) * CA + w * 1024 + half * 512 + lane * 8;
    const size_t BbS = (size_t)n0 * CB + w * 512 + lane * 8;
    const size_t AbN = (size_t)(m0 & ~127) * CA + half * 512 + lane * 8;
    const size_t BbN = (size_t)n0 * CB + lane * 8;

    auto STAGE = [&](int t, int cur) {
        short* bp = &lds[cur * BUF];
        if constexpr (SPLITM == 1) {
            const size_t kk = (size_t)t << 12;
            gload16(Ah + AbS + kk, bp + w * 512);
            gload16(Bh + BbS + kk, bp + BHO + w * 512);
            gload16(Bh + BbS + kk + 2048, bp + BHO + 2048 + w * 512);
            gload16(Al + AbS + kk, bp + ALO + w * 512);
            gload16(Bl + BbS + kk, bp + BLO + w * 512);
            gload16(Bl + BbS + kk + 2048, bp + BLO + 2048 + w * 512);
        } else if constexpr (SPLITM == 2) {
            const size_t kk = (size_t)t << 12;
            gload16(Ah + AbS + kk, bp + w * 512);
            gload16(Bh + BbS + kk, bp + BHO + w * 512);
            gload16(Bh + BbS + kk + 2048, bp + BHO + 2048 + w * 512);
            gload16(Bl + BbS + kk, bp + BLO + w * 512);
            gload16(Bl + BbS + kk + 2048, bp + BLO + 2048 + w * 512);
        } else {
            const size_t kk = (size_t)t << 13;
            const int cs0 = 2 * w, cs1 = 2 * w + 1;
            gload16(Ah + AbN + kk + cs0 * 1024, bp + cs0 * 512);
            gload16(Ah + AbN + kk + cs1 * 1024, bp + cs1 * 512);
            gload16(Bh + BbN + kk + cs0 * 1024,       bp + BHO + cs0 * 1024);
            gload16(Bh + BbN + kk + cs0 * 1024 + 512, bp + BHO + cs0 * 1024 + 512);
            gload16(Bh + BbN + kk + cs1 * 1024,       bp + BHO + cs1 * 1024);
            gload16(Bh + BbN + kk + cs1 * 1024 + 512, bp + BHO + cs1 * 1024 + 512);
        }
    };

    STAGE(0, 0);

    for (int t = 0; t < nk; ++t) {
        __syncthreads();
        if (t + 1 < nk) STAGE(t + 1, (t + 1) & 1);
        const short* bs = &lds[(t & 1) * BUF];

        #pragma unroll
        for (int ks = 0; ks < (SPLITM ? 1 : 2); ++ks) {
            const int c = ks * 4 + kg;
            s16x8 a[2], b[4];
            #pragma unroll
            for (int g = 0; g < 2; ++g)
                a[g] = *(const s16x8*)&bs[c * 512 + (wr * 32 + g * 16 + fm) * 8];
            #pragma unroll
            for (int h = 0; h < 4; ++h)
                b[h] = *(const s16x8*)&bs[BHO + c * 1024 + (wc * 64 + h * 16 + fm) * 8];
            if constexpr (SPLITM == 1) {
                s16x8 a2[2], b2[4];
                #pragma unroll
                for (int g = 0; g < 2; ++g)
                    a2[g] = *(const s16x8*)&bs[ALO + c * 512 + (wr * 32 + g * 16 + fm) * 8];
                #pragma unroll
                for (int h = 0; h < 4; ++h)
                    b2[h] = *(const s16x8*)&bs[BLO + c * 1024 + (wc * 64 + h * 16 + fm) * 8];
                #pragma unroll
                for (int g = 0; g < 2; ++g)
                    #pragma unroll
                    for (int h = 0; h < 4; ++h) {
                        acc[g][h] = __builtin_amdgcn_mfma_f32_16x16x32_bf16(a[g], b[h], acc[g][h], 0, 0, 0);
                        acc[g][h] = __builtin_amdgcn_mfma_f32_16x16x32_bf16(a[g], b2[h], acc[g][h], 0, 0, 0);
                        acc[g][h] = __builtin_amdgcn_mfma_f32_16x16x32_bf16(a2[g], b[h], acc[g][h], 0, 0, 0);
                    }
            } else if constexpr (SPLITM == 2) {
                s16x8 b2[4];
                #pragma unroll
                for (int h = 0; h < 4; ++h)
                    b2[h] = *(const s16x8*)&bs[BLO + c * 1024 + (wc * 64 + h * 16 + fm) * 8];
                #pragma unroll
                for (int g = 0; g < 2; ++g)
                    #pragma unroll
                    for (int h = 0; h < 4; ++h) {
                        acc[g][h] = __builtin_amdgcn_mfma_f32_16x16x32_bf16(a[g], b[h], acc[g][h], 0, 0, 0);
                        acc[g][h] = __builtin_amdgcn_mfma_f32_16x16x32_bf16(a[g], b2[h], acc[g][h], 0, 0, 0);
                    }
            } else {
                #pragma unroll
                for (int g = 0; g < 2; ++g)
                    #pragma unroll
                    for (int h = 0; h < 4; ++h)
                        acc[g][h] = __builtin_amdgcn_mfma_f32_16x16x32_bf16(a[g], b[h], acc[g][h], 0, 0, 0);
            }
        }
    }

    // epilogue: frag (row = kg*4+j, col = fm)
    #pragma unroll
    for (int g = 0; g < 2; ++g) {
        #pragma unroll
        for (int h = 0; h < 4; ++h) {
            #pragma unroll
            for (int j = 0; j < 4; ++j) {
                int m = m0 + wr * 32 + g * 16 + kg * 4 + j;
                int n = n0 + wc * 64 + h * 16 + fm;
                float v = acc[g][h][j];
                if (EPI == 0) {
                    if (n < DS) Out[(size_t)m * DS + n] = v;
                } else if (EPI == 3) {
                    size_t pz = (size_t)(m & ~127) * NG + ((n >> 3) << 10) +
                                ((m & 127) << 3) + (n & 7);
                    Ynew[pz] = f2s(v * invL);
                } else {  // EPI == 4
                    Grm[(size_t)m * NG + n] = f2s(v);
                }
            }
        }
    }
}

// ---------------------------------------------------------------------------
// Launch
// ---------------------------------------------------------------------------
extern "C" void kernel_launch(void* const* d_in, const int* in_sizes, int n_in,
                              void* d_out, int out_size, void* d_ws, size_t ws_size,
                              hipStream_t stream) {
    const float* x = (const float*)d_in[0];   // (2048, 1200)
    const float* D = (const float*)d_in[1];   // (1200, 2400)
    float* out = (float*)d_out;               // (2048, 1200)

    char* wsb = (char*)d_ws;
    float* w0 = (float*)wsb;                  // 2432
    float* w1 = w0 + 2432;
    float* part = w1 + 2432;                  // 21*150
    float* scal = part + 3200;                // 3

    char* p = wsb + 65536;
    short* Dp   = (short*)p; p += (size_t)NP1 * NG * 2;    // 6.2 MB
    short* Dthi = (short*)p; p += (size_t)NG * KP * 2;     // 5.9 MB
    short* Dtlo = (short*)p; p += (size_t)NG * KP * 2;
    short* Xp   = (short*)p; p += (size_t)MR * KP * 2;     // 5.0 MB
    short* Wp   = (short*)p; p += (size_t)NG * NG * 2;     // 11.8 MB (packed W)
    short* Grm  = (short*)p; p += (size_t)NG * NG * 2;     // 11.8 MB (bf16 G, rm)
    short* XDLp = (short*)p; p += (size_t)MR * NG * 2;     // 10 MB (bf16 XD/L)
    short* Ya   = (short*)p; p += (size_t)MR * NG * 2;     // 10 MB
    short* Yb   = (short*)p; p += (size_t)MR * NG * 2;     // 10 MB
    short* Zp   = (short*)p; p += (size_t)MR * NG * 2;     // 10 MB

    // ---- prep ----
    k_makeD<<<(NP1 * NG + 255) / 256, 256, 0, stream>>>(D, Dp);
    k_makeDt<<<dim3(NG / 32, KP / 32), 256, 0, stream>>>(D, Dthi, Dtlo);
    k_makeX<<<(MR * KP + 255) / 256, 256, 0, stream>>>(x, Xp);

    // ---- G = D^T D (both split, high precision) -> Grm bf16 row-major ----
    mfma_gemm<4, 1><<<dim3(NG / 128, NG / 64), 256, 0, stream>>>(
        Dthi, Dtlo, KP, Dthi, Dtlo, KP, KP, 0,
        nullptr, nullptr, Grm, nullptr);

    // ---- power iteration on Grm (20-launch chain) ----
    k_init<<<1, 256, 0, stream>>>(w0, w1, part);
    for (int j = 0; j < 20; j++) {
        const float* win = (j & 1) ? w1 : w0;
        float* wout = (j & 1) ? w0 : w1;
        k_gmv<<<PPI, 1024, 0, stream>>>(Grm, win, part + j * PPI, wout,
                                        part + (j + 1) * PPI);
    }
    k_fin<<<1, 64, 0, stream>>>(part + 20 * PPI, scal);

    // ---- W = I - G/L (bf16, packed) from bf16 Grm ----
    k_makeW<<<(NG * NG / 8 + 255) / 256, 256, 0, stream>>>(Grm, scal, Wp);

    // ---- XDL = (x @ D) / L (A single, B split; bf16 packed out) ----
    mfma_gemm<3, 2><<<dim3(608), 256, 0, stream>>>(
        Xp, nullptr, KP, Dthi, Dtlo, KP, KP, 1,
        scal, XDLp, nullptr, nullptr);

    // ---- FISTA iter 0 (elementwise): z1 = soft(XDL), y1 = z1 ----
    k_fista0<<<(MR * NG / 8 + 255) / 256, 256, 0, stream>>>(XDLp, scal, Zp, Ya);

    // ---- FISTA iters 1..14: z = soft(yW + XDL); y ping-pong ----
    float t = 1.6180339887f;   // t after iter 0
    for (int i = 1; i < 15; i++) {
        float tn = 0.5f * (1.0f + sqrtf(1.0f + 4.0f * t * t));
        float mom = (t - 1.0f) / tn;
        t = tn;
        short* Yc = (i & 1) ? Ya : Yb;
        short* Yn = (i & 1) ? Yb : Ya;
        fista_gemm<<<dim3(608), 256, 0, stream>>>(
            Yc, Wp, XDLp, scal, mom, Yn, Zp, 0);
    }
    // ---- FISTA iter 15: z only (y16 never consumed) ----
    fista_gemm<<<dim3(608), 256, 0, stream>>>(
        Ya, Wp, XDLp, scal, 0.0f, nullptr, Zp, 1);

    // ---- final recon = z @ D^T -> out ----
    mfma_gemm<0, 0><<<dim3(320), 256, 0, stream>>>(
        Zp, nullptr, NG, Dp, nullptr, NG, NG, 1,
        nullptr, nullptr, nullptr, out);
}

// Round 14
// 856.389 us; speedup vs baseline: 1.3261x; 1.3261x over previous
//
#include <hip/hip_runtime.h>
#include <hip/hip_bf16.h>
#include <cmath>

// ---------------------------------------------------------------------------
// Sizes
// ---------------------------------------------------------------------------
#define DS 1200     // signal dim
#define DD 2400     // dict dim
#define MR 2048     // rows (B*N)
#define KP 1216     // padded signal dim (38*32)
#define NP1 1280    // padded signal dim for recon B panel (10*128)
#define NG 2432     // padded dict dim (19*128 = 38*64)
#define PPI 150     // norm partials per power iteration

typedef __attribute__((ext_vector_type(8))) short s16x8;
typedef __attribute__((ext_vector_type(4))) float f32x4;

__device__ __forceinline__ float s2f(short s) {
    union { unsigned u; float f; } c;
    c.u = ((unsigned)(unsigned short)s) << 16;
    return c.f;
}
__device__ __forceinline__ short f2s(float f) {
    __hip_bfloat16 h = __float2bfloat16(f);
    return *reinterpret_cast<short*>(&h);
}

// Packed layout: 128-row bands; within a band, 8-col k-subtiles of 1024 elems:
//   poff(m,k,C) = (m&~127)*C + (k>>3)*1024 + (m&127)*8 + (k&7)

// ---------------------------------------------------------------------------
// JAX threefry2x32 + XLA f32 erfinv (reproduce jax.random.normal(key(42)))
// ---------------------------------------------------------------------------
__device__ __forceinline__ unsigned rotl32(unsigned x, int d) {
    return (x << d) | (x >> (32 - d));
}

__device__ void threefry2x32(unsigned k0, unsigned k1, unsigned x0, unsigned x1,
                             unsigned* o0, unsigned* o1) {
    unsigned ks0 = k0, ks1 = k1, ks2 = k0 ^ k1 ^ 0x1BD11BDAu;
    const int rotA[4] = {13, 15, 26, 6};
    const int rotB[4] = {17, 29, 16, 24};
    x0 += ks0; x1 += ks1;
    #pragma unroll
    for (int r = 0; r < 4; r++) { x0 += x1; x1 = rotl32(x1, rotA[r]); x1 ^= x0; }
    x0 += ks1; x1 += ks2 + 1u;
    #pragma unroll
    for (int r = 0; r < 4; r++) { x0 += x1; x1 = rotl32(x1, rotB[r]); x1 ^= x0; }
    x0 += ks2; x1 += ks0 + 2u;
    #pragma unroll
    for (int r = 0; r < 4; r++) { x0 += x1; x1 = rotl32(x1, rotA[r]); x1 ^= x0; }
    x0 += ks0; x1 += ks1 + 3u;
    #pragma unroll
    for (int r = 0; r < 4; r++) { x0 += x1; x1 = rotl32(x1, rotB[r]); x1 ^= x0; }
    x0 += ks1; x1 += ks2 + 4u;
    #pragma unroll
    for (int r = 0; r < 4; r++) { x0 += x1; x1 = rotl32(x1, rotA[r]); x1 ^= x0; }
    x0 += ks2; x1 += ks0 + 5u;
    *o0 = x0; *o1 = x1;
}

__device__ float erfinv_f32(float x) {
    float w = -logf((1.0f - x) * (1.0f + x));
    float p;
    if (w < 5.0f) {
        w -= 2.5f;
        p = 2.81022636e-08f;
        p = fmaf(p, w, 3.43273939e-07f);
        p = fmaf(p, w, -3.5233877e-06f);
        p = fmaf(p, w, -4.39150654e-06f);
        p = fmaf(p, w, 0.00021858087f);
        p = fmaf(p, w, -0.00125372503f);
        p = fmaf(p, w, -0.00417768164f);
        p = fmaf(p, w, 0.246640727f);
        p = fmaf(p, w, 1.50140941f);
    } else {
        w = sqrtf(w) - 3.0f;
        p = -0.000200214257f;
        p = fmaf(p, w, 0.000100950558f);
        p = fmaf(p, w, 0.00134934322f);
        p = fmaf(p, w, -0.00367342844f);
        p = fmaf(p, w, 0.00573950773f);
        p = fmaf(p, w, -0.0076224613f);
        p = fmaf(p, w, 0.00943887047f);
        p = fmaf(p, w, 1.00167406f);
        p = fmaf(p, w, 2.83297682f);
    }
    return p * x;
}

__device__ float bits_to_normal(unsigned bits) {
    unsigned fb = (bits >> 9) | 0x3F800000u;
    float u01 = __uint_as_float(fb) - 1.0f;
    const float lo = -0.99999994f;
    float u = u01 * 2.0f + lo;
    u = fmaxf(lo, u);
    return 1.41421356237f * erfinv_f32(u);
}

// ---------------------------------------------------------------------------
// Power iteration (20-launch chain, deterministic fixed-slot partials)
// ---------------------------------------------------------------------------
__global__ void k_init(float* __restrict__ w0, float* __restrict__ w1,
                       float* __restrict__ part) {
    int tid = threadIdx.x;
    for (int i = tid; i < 21 * PPI; i += 256) part[i] = 0.0f;
    if (tid < 32) {
        w0[2400 + tid] = 0.0f;
        w1[2400 + tid] = 0.0f;
    }
    __shared__ float red[256];
    float local2 = 0.0f;
    for (int p = tid; p < DS; p += 256) {
        unsigned r0, r1;
        threefry2x32(0u, 42u, (unsigned)p, (unsigned)(DS + p), &r0, &r1);
        float n0 = bits_to_normal(r0);
        float n1 = bits_to_normal(r1);
        w0[p] = n0;
        w0[DS + p] = n1;
        local2 += n0 * n0 + n1 * n1;
    }
    red[tid] = local2;
    __syncthreads();
    for (int s = 128; s > 0; s >>= 1) {
        if (tid < s) red[tid] += red[tid + s];
        __syncthreads();
    }
    if (tid == 0) part[0] = red[0];
}

__global__ __launch_bounds__(1024) void k_gmv(const short* __restrict__ Grm,
                                              const float* __restrict__ win,
                                              const float* __restrict__ partin,
                                              float* __restrict__ wout,
                                              float* __restrict__ partout) {
    float s2 = 0.0f;
    for (int i = 0; i < PPI; i++) s2 += partin[i];
    float rn = 1.0f / sqrtf(s2);
    int wave = threadIdx.x >> 6, lane = threadIdx.x & 63;
    int row = blockIdx.x * 16 + wave;       // 150 * 16 = 2400 rows
    const s16x8* gh = (const s16x8*)(Grm + (size_t)row * NG);
    const float4* w4 = (const float4*)win;
    float acc = 0.0f;
    #pragma unroll
    for (int i = 0; i < 5; i++) {
        int c = lane + i * 64;              // 304 chunks
        if (c < 304) {
            s16x8 h = gh[c];
            float4 wa = w4[c * 2], wb = w4[c * 2 + 1];
            acc += s2f(h[0]) * wa.x + s2f(h[1]) * wa.y;
            acc += s2f(h[2]) * wa.z + s2f(h[3]) * wa.w;
            acc += s2f(h[4]) * wb.x + s2f(h[5]) * wb.y;
            acc += s2f(h[6]) * wb.z + s2f(h[7]) * wb.w;
        }
    }
    #pragma unroll
    for (int off = 32; off > 0; off >>= 1) acc += __shfl_xor(acc, off, 64);
    __shared__ float red[16];
    if (lane == 0) {
        float val = acc * rn;
        wout[row] = val;
        red[wave] = val * val;
    }
    __syncthreads();
    if (threadIdx.x == 0) {
        float s = 0.0f;
        #pragma unroll
        for (int i = 0; i < 16; i++) s += red[i];
        partout[blockIdx.x] = s;
    }
}

__global__ void k_fin(const float* __restrict__ part20, float* __restrict__ scal) {
    if (threadIdx.x == 0) {
        float s = 0.0f;
        for (int i = 0; i < PPI; i++) s += part20[i];
        float L = sqrtf(s);
        scal[0] = L;
        scal[1] = 1.0f / L;
        scal[2] = 0.1f / L;
    }
}

// ---------------------------------------------------------------------------
// Prep kernels (write packed layouts)
// ---------------------------------------------------------------------------
__global__ void k_makeD(const float* __restrict__ D, short* __restrict__ Dp) {
    int p = blockIdx.x * 256 + threadIdx.x;     // NP1*NG
    if (p >= NP1 * NG) return;
    int tile = p >> 10, win = p & 1023;
    int row = win >> 3, e = win & 7;
    int mt = tile / (NG >> 3), ct = tile % (NG >> 3);
    int d = mt * 128 + row, n = ct * 8 + e;
    float v = (d < DS && n < DD) ? D[(size_t)d * DD + n] : 0.0f;
    Dp[p] = f2s(v);
}

// X packed single-bf16 (A operand of XDL GEMM)
__global__ void k_makeX(const float* __restrict__ x, short* __restrict__ Xp) {
    int p = blockIdx.x * 256 + threadIdx.x;     // MR*KP
    if (p >= MR * KP) return;
    int tile = p >> 10, win = p & 1023;
    int row = win >> 3, e = win & 7;
    int mt = tile / (KP >> 3), ct = tile % (KP >> 3);
    int m = mt * 128 + row, k = ct * 8 + e;
    float v = (k < DS) ? x[(size_t)m * DS + k] : 0.0f;
    Xp[p] = f2s(v);
}

__global__ void k_makeDt(const float* __restrict__ D,
                         short* __restrict__ Dthi, short* __restrict__ Dtlo) {
    __shared__ float t[32][33];
    int bc = blockIdx.x * 32;   // dict base
    int bk = blockIdx.y * 32;   // signal base
    int tx = threadIdx.x & 31, ty = threadIdx.x >> 5;
    for (int i = ty; i < 32; i += 8) {
        int k = bk + i, c = bc + tx;
        t[i][tx] = (k < DS && c < DD) ? D[(size_t)k * DD + c] : 0.0f;
    }
    __syncthreads();
    for (int i = ty; i < 32; i += 8) {
        int c = bc + i, k = bk + tx;
        float v = t[tx][i];
        short h = f2s(v);
        size_t po = ((size_t)(c >> 7) * (KP >> 3) + (k >> 3)) * 1024 +
                    ((c & 127) << 3) + (k & 7);
        Dthi[po] = h;
        Dtlo[po] = f2s(v - s2f(h));
    }
}

// W = I - G/L, bf16 packed layout, from bf16 row-major Grm.
__global__ void k_makeW(const short* __restrict__ Grm, const float* __restrict__ scal,
                        short* __restrict__ Wp) {
    int i = blockIdx.x * 256 + threadIdx.x;      // over NG*NG/8
    if (i >= NG * NG / 8) return;
    float invL = scal[1];
    int e0 = i * 8;
    int band = e0 / (128 * NG);
    int rem = e0 - band * (128 * NG);
    int tile = rem >> 10;
    int row = (rem & 1023) >> 3;
    int m = band * 128 + row;       // W row (output index n)
    int k0 = tile * 8;              // W col (contraction index k)
    s16x8 g = *(const s16x8*)(Grm + (size_t)m * NG + k0);
    s16x8 wv;
    #pragma unroll
    for (int e = 0; e < 8; e++) {
        float wf = ((k0 + e == m) ? 1.0f : 0.0f) - s2f(g[e]) * invL;
        wv[e] = f2s(wf);
    }
    ((s16x8*)Wp)[i] = wv;
}

// FISTA iteration 0 (y0=0): z1 = soft(XDL, thr); y1 = z1.
__global__ void k_fista0(const short* __restrict__ XDL, const float* __restrict__ scal,
                         short* __restrict__ Z, short* __restrict__ Y) {
    int i = blockIdx.x * 256 + threadIdx.x;      // over MR*NG/8
    if (i >= MR * NG / 8) return;
    float thr = scal[2];
    s16x8 xv = ((const s16x8*)XDL)[i];
    s16x8 zs;
    #pragma unroll
    for (int k = 0; k < 8; k++) {
        float gs = s2f(xv[k]);
        float az = fabsf(gs) - thr;
        float zn = (az > 0.0f) ? copysignf(az, gs) : 0.0f;
        zs[k] = f2s(zn);
    }
    ((s16x8*)Z)[i] = zs;
    ((s16x8*)Y)[i] = zs;
}

// ---------------------------------------------------------------------------
__device__ __forceinline__ void gload16(const void* g, void* l) {
    __builtin_amdgcn_global_load_lds(
        (const __attribute__((address_space(1))) unsigned int*)g,
        (__attribute__((address_space(3))) unsigned int*)l, 16, 0, 0);
}

// ---------------------------------------------------------------------------
// MFMA GEMM on packed operands (R7-proven 2-buffer structure). Tile 64x128,
// 4 waves (32x64).
// SPLITM: 0 = single bf16 (BK=64), 1 = A&B hi/lo split (BK=32, 3 MFMA),
//         2 = B-only split (BK=32, 2 MFMA).
// EPI 0: Out[m*DS+n] = acc (n<DS)        (final recon)
// EPI 2: FISTA: gs=acc+XDL[pz]; z=soft(gs); ynext=z+mom*(z-zold)
// EPI 3: XDLout[pz] = bf16(acc*invL)     (XDL precompute; via Ynew)
// EPI 4: Grm[m*NG+n] = bf16(acc)         (G precompute)
// EPI 5: FISTA last iter: z only (no y write, no zold read)
// ---------------------------------------------------------------------------
template <int EPI, int SPLITM>
__global__ __launch_bounds__(256, 4) void mfma_gemm(
    const short* __restrict__ Ah, const short* __restrict__ Al, int CA,
    const short* __restrict__ Bh, const short* __restrict__ Bl, int CB,
    int K, int swz,
    const short* __restrict__ XDLp, const float* __restrict__ scal, float mom,
    short* __restrict__ Ynew, short* __restrict__ Zst,
    short* __restrict__ Grm,
    float* __restrict__ Out) {
    constexpr int ALO = 2048;
    constexpr int BHO = 4096;
    constexpr int BLO = 8192;
    constexpr int BUF = 12288;                // 24 KB per buffer
    __shared__ __align__(16) short lds[2 * BUF];

    const int tid = threadIdx.x;
    const int w = tid >> 6, lane = tid & 63;
    const int fm = lane & 15, kg = lane >> 4;
    const int wr = w >> 1, wc = w & 1;

    int bx, by;
    if (swz) {                                // grid divisible by 8
        int q = gridDim.x >> 3;
        int s = (blockIdx.x & 7) * q + (blockIdx.x >> 3);
        by = s & 31; bx = s >> 5;             // 32 M-blocks (M=2048)
    } else { bx = blockIdx.x; by = blockIdx.y; }
    const int m0 = by * 64, n0 = bx * 128;

    f32x4 acc[2][4];
    #pragma unroll
    for (int g = 0; g < 2; ++g)
        #pragma unroll
        for (int h = 0; h < 4; ++h) acc[g][h] = f32x4{0.f, 0.f, 0.f, 0.f};

    float invL = 0.0f, thr = 0.0f;
    if (EPI == 2 || EPI == 5) thr = scal[2];
    if (EPI == 3) invL = scal[1];

    const int half = (m0 >> 6) & 1;
    const int nk = K / (SPLITM ? 32 : 64);

    const size_t AbS = (size_t)(m0 & ~127) * CA + w * 1024 + half * 512 + lane * 8;
    const size_t BbS = (size_t)n0 * CB + w * 512 + lane * 8;
    const size_t AbN = (size_t)(m0 & ~127) * CA + half * 512 + lane * 8;
    const size_t BbN = (size_t)n0 * CB + lane * 8;

    auto STAGE = [&](int t, int cur) {
        short* bp = &lds[cur * BUF];
        if constexpr (SPLITM == 1) {
            const size_t kk = (size_t)t << 12;
            gload16(Ah + AbS + kk, bp + w * 512);
            gload16(Bh + BbS + kk, bp + BHO + w * 512);
            gload16(Bh + BbS + kk + 2048, bp + BHO + 2048 + w * 512);
            gload16(Al + AbS + kk, bp + ALO + w * 512);
            gload16(Bl + BbS + kk, bp + BLO + w * 512);
            gload16(Bl + BbS + kk + 2048, bp + BLO + 2048 + w * 512);
        } else if constexpr (SPLITM == 2) {
            const size_t kk = (size_t)t << 12;
            gload16(Ah + AbS + kk, bp + w * 512);
            gload16(Bh + BbS + kk, bp + BHO + w * 512);
            gload16(Bh + BbS + kk + 2048, bp + BHO + 2048 + w * 512);
            gload16(Bl + BbS + kk, bp + BLO + w * 512);
            gload16(Bl + BbS + kk + 2048, bp + BLO + 2048 + w * 512);
        } else {
            const size_t kk = (size_t)t << 13;
            const int cs0 = 2 * w, cs1 = 2 * w + 1;
            gload16(Ah + AbN + kk + cs0 * 1024, bp + cs0 * 512);
            gload16(Ah + AbN + kk + cs1 * 1024, bp + cs1 * 512);
            gload16(Bh + BbN + kk + cs0 * 1024,       bp + BHO + cs0 * 1024);
            gload16(Bh + BbN + kk + cs0 * 1024 + 512, bp + BHO + cs0 * 1024 + 512);
            gload16(Bh + BbN + kk + cs1 * 1024,       bp + BHO + cs1 * 1024);
            gload16(Bh + BbN + kk + cs1 * 1024 + 512, bp + BHO + cs1 * 1024 + 512);
        }
    };

    STAGE(0, 0);

    for (int t = 0; t < nk; ++t) {
        __syncthreads();
        if (t + 1 < nk) STAGE(t + 1, (t + 1) & 1);
        const short* bs = &lds[(t & 1) * BUF];

        #pragma unroll
        for (int ks = 0; ks < (SPLITM ? 1 : 2); ++ks) {
            const int c = ks * 4 + kg;
            s16x8 a[2], b[4];
            #pragma unroll
            for (int g = 0; g < 2; ++g)
                a[g] = *(const s16x8*)&bs[c * 512 + (wr * 32 + g * 16 + fm) * 8];
            #pragma unroll
            for (int h = 0; h < 4; ++h)
                b[h] = *(const s16x8*)&bs[BHO + c * 1024 + (wc * 64 + h * 16 + fm) * 8];
            if constexpr (SPLITM == 1) {
                s16x8 a2[2], b2[4];
                #pragma unroll
                for (int g = 0; g < 2; ++g)
                    a2[g] = *(const s16x8*)&bs[ALO + c * 512 + (wr * 32 + g * 16 + fm) * 8];
                #pragma unroll
                for (int h = 0; h < 4; ++h)
                    b2[h] = *(const s16x8*)&bs[BLO + c * 1024 + (wc * 64 + h * 16 + fm) * 8];
                #pragma unroll
                for (int g = 0; g < 2; ++g)
                    #pragma unroll
                    for (int h = 0; h < 4; ++h) {
                        acc[g][h] = __builtin_amdgcn_mfma_f32_16x16x32_bf16(a[g], b[h], acc[g][h], 0, 0, 0);
                        acc[g][h] = __builtin_amdgcn_mfma_f32_16x16x32_bf16(a[g], b2[h], acc[g][h], 0, 0, 0);
                        acc[g][h] = __builtin_amdgcn_mfma_f32_16x16x32_bf16(a2[g], b[h], acc[g][h], 0, 0, 0);
                    }
            } else if constexpr (SPLITM == 2) {
                s16x8 b2[4];
                #pragma unroll
                for (int h = 0; h < 4; ++h)
                    b2[h] = *(const s16x8*)&bs[BLO + c * 1024 + (wc * 64 + h * 16 + fm) * 8];
                #pragma unroll
                for (int g = 0; g < 2; ++g)
                    #pragma unroll
                    for (int h = 0; h < 4; ++h) {
                        acc[g][h] = __builtin_amdgcn_mfma_f32_16x16x32_bf16(a[g], b[h], acc[g][h], 0, 0, 0);
                        acc[g][h] = __builtin_amdgcn_mfma_f32_16x16x32_bf16(a[g], b2[h], acc[g][h], 0, 0, 0);
                    }
            } else {
                #pragma unroll
                for (int g = 0; g < 2; ++g)
                    #pragma unroll
                    for (int h = 0; h < 4; ++h)
                        acc[g][h] = __builtin_amdgcn_mfma_f32_16x16x32_bf16(a[g], b[h], acc[g][h], 0, 0, 0);
            }
        }
    }

    // epilogue: frag (row = kg*4+j, col = fm)
    #pragma unroll
    for (int g = 0; g < 2; ++g) {
        #pragma unroll
        for (int h = 0; h < 4; ++h) {
            #pragma unroll
            for (int j = 0; j < 4; ++j) {
                int m = m0 + wr * 32 + g * 16 + kg * 4 + j;
                int n = n0 + wc * 64 + h * 16 + fm;
                float v = acc[g][h][j];
                if (EPI == 0) {
                    if (n < DS) Out[(size_t)m * DS + n] = v;
                } else if (EPI == 2) {
                    size_t pz = (size_t)(m & ~127) * NG + ((n >> 3) << 10) +
                                ((m & 127) << 3) + (n & 7);
                    float gs = v + s2f(XDLp[pz]);
                    float az = fabsf(gs) - thr;
                    float zn = (az > 0.0f) ? copysignf(az, gs) : 0.0f;
                    float zold = s2f(Zst[pz]);
                    float yn = zn + mom * (zn - zold);
                    Zst[pz] = f2s(zn);
                    Ynew[pz] = f2s(yn);
                } else if (EPI == 5) {
                    size_t pz = (size_t)(m & ~127) * NG + ((n >> 3) << 10) +
                                ((m & 127) << 3) + (n & 7);
                    float gs = v + s2f(XDLp[pz]);
                    float az = fabsf(gs) - thr;
                    float zn = (az > 0.0f) ? copysignf(az, gs) : 0.0f;
                    Zst[pz] = f2s(zn);
                } else if (EPI == 3) {
                    size_t pz = (size_t)(m & ~127) * NG + ((n >> 3) << 10) +
                                ((m & 127) << 3) + (n & 7);
                    Ynew[pz] = f2s(v * invL);
                } else {  // EPI == 4
                    Grm[(size_t)m * NG + n] = f2s(v);
                }
            }
        }
    }
}

// ---------------------------------------------------------------------------
// Launch
// ---------------------------------------------------------------------------
extern "C" void kernel_launch(void* const* d_in, const int* in_sizes, int n_in,
                              void* d_out, int out_size, void* d_ws, size_t ws_size,
                              hipStream_t stream) {
    const float* x = (const float*)d_in[0];   // (2048, 1200)
    const float* D = (const float*)d_in[1];   // (1200, 2400)
    float* out = (float*)d_out;               // (2048, 1200)

    char* wsb = (char*)d_ws;
    float* w0 = (float*)wsb;                  // 2432
    float* w1 = w0 + 2432;
    float* part = w1 + 2432;                  // 21*150
    float* scal = part + 3200;                // 3

    char* p = wsb + 65536;
    short* Dp   = (short*)p; p += (size_t)NP1 * NG * 2;    // 6.2 MB
    short* Dthi = (short*)p; p += (size_t)NG * KP * 2;     // 5.9 MB
    short* Dtlo = (short*)p; p += (size_t)NG * KP * 2;
    short* Xp   = (short*)p; p += (size_t)MR * KP * 2;     // 5.0 MB
    short* Wp   = (short*)p; p += (size_t)NG * NG * 2;     // 11.8 MB (packed W)
    short* Grm  = (short*)p; p += (size_t)NG * NG * 2;     // 11.8 MB (bf16 G, rm)
    short* XDLp = (short*)p; p += (size_t)MR * NG * 2;     // 10 MB (bf16 XD/L)
    short* Ya   = (short*)p; p += (size_t)MR * NG * 2;     // 10 MB
    short* Yb   = (short*)p; p += (size_t)MR * NG * 2;     // 10 MB
    short* Zp   = (short*)p; p += (size_t)MR * NG * 2;     // 10 MB

    // ---- prep ----
    k_makeD<<<(NP1 * NG + 255) / 256, 256, 0, stream>>>(D, Dp);
    k_makeDt<<<dim3(NG / 32, KP / 32), 256, 0, stream>>>(D, Dthi, Dtlo);
    k_makeX<<<(MR * KP + 255) / 256, 256, 0, stream>>>(x, Xp);

    // ---- G = D^T D (both split, high precision) -> Grm bf16 row-major ----
    mfma_gemm<4, 1><<<dim3(NG / 128, NG / 64), 256, 0, stream>>>(
        Dthi, Dtlo, KP, Dthi, Dtlo, KP, KP, 0,
        nullptr, nullptr, 0.0f, nullptr, nullptr, Grm, nullptr);

    // ---- power iteration on Grm (20-launch chain) ----
    k_init<<<1, 256, 0, stream>>>(w0, w1, part);
    for (int j = 0; j < 20; j++) {
        const float* win = (j & 1) ? w1 : w0;
        float* wout = (j & 1) ? w0 : w1;
        k_gmv<<<PPI, 1024, 0, stream>>>(Grm, win, part + j * PPI, wout,
                                        part + (j + 1) * PPI);
    }
    k_fin<<<1, 64, 0, stream>>>(part + 20 * PPI, scal);

    // ---- W = I - G/L (bf16, packed) from bf16 Grm ----
    k_makeW<<<(NG * NG / 8 + 255) / 256, 256, 0, stream>>>(Grm, scal, Wp);

    // ---- XDL = (x @ D) / L (A single, B split; bf16 packed out) ----
    mfma_gemm<3, 2><<<dim3(608), 256, 0, stream>>>(
        Xp, nullptr, KP, Dthi, Dtlo, KP, KP, 1,
        nullptr, scal, 0.0f, XDLp, nullptr, nullptr, nullptr);

    // ---- FISTA iter 0 (elementwise): z1 = soft(XDL), y1 = z1 ----
    k_fista0<<<(MR * NG / 8 + 255) / 256, 256, 0, stream>>>(XDLp, scal, Zp, Ya);

    // ---- FISTA iters 1..14: z = soft(yW + XDL); y ping-pong ----
    float t = 1.6180339887f;   // t after iter 0
    for (int i = 1; i < 15; i++) {
        float tn = 0.5f * (1.0f + sqrtf(1.0f + 4.0f * t * t));
        float mom = (t - 1.0f) / tn;
        t = tn;
        short* Yc = (i & 1) ? Ya : Yb;
        short* Yn = (i & 1) ? Yb : Ya;
        mfma_gemm<2, 0><<<dim3(608), 256, 0, stream>>>(
            Yc, nullptr, NG, Wp, nullptr, NG, NG, 1,
            XDLp, scal, mom, Yn, Zp, nullptr, nullptr);
    }
    // ---- FISTA iter 15: z only (y16 never consumed) ----
    {
        short* Yc = Ya;   // i=15 odd -> current y is Ya
        mfma_gemm<5, 0><<<dim3(608), 256, 0, stream>>>(
            Yc, nullptr, NG, Wp, nullptr, NG, NG, 1,
            XDLp, scal, 0.0f, nullptr, Zp, nullptr, nullptr);
    }

    // ---- final recon = z @ D^T -> out ----
    mfma_gemm<0, 0><<<dim3(320), 256, 0, stream>>>(
        Zp, nullptr, NG, Dp, nullptr, NG, NG, 1,
        nullptr, nullptr, 0.0f, nullptr, nullptr, nullptr, out);
}